// Round 1
// baseline (1175.419 us; speedup 1.0000x reference)
//
#include <hip/hip_runtime.h>
#include <hip/hip_bf16.h>

// APPNP propagation on MI355X.
// Strategy: build CSR-by-dst once per launch (ws is re-poisoned every call),
// then K=10 gather iterations, 1 wave per node / 1 lane per feature column.

#define D_FEAT 64
#define K_ITERS 10
#define ALPHA 0.1f

// ---------------------------------------------------------------- degree count
__global__ void count_deg_kernel(const int* __restrict__ dst, int* __restrict__ deg, int e) {
    int i = blockIdx.x * blockDim.x + threadIdx.x;
    if (i < e) atomicAdd(&deg[dst[i]], 1);
}

// ------------------------------------------------ single-block scan + norm calc
// 1024 threads; each thread owns a contiguous chunk of nodes.
__global__ void scan_kernel(const int* __restrict__ deg, int* __restrict__ row_ptr,
                            float* __restrict__ norm, int n, int e_total) {
    __shared__ int part[1024];
    const int tid = threadIdx.x;
    const int chunk = (n + 1023) / 1024;
    const int beg = tid * chunk;
    const int end = min(beg + chunk, n);

    int sum = 0;
    for (int i = beg; i < end; ++i) sum += deg[i];
    part[tid] = sum;
    __syncthreads();

    // Hillis-Steele inclusive scan over the 1024 partials.
    for (int off = 1; off < 1024; off <<= 1) {
        int t = (tid >= off) ? part[tid - off] : 0;
        __syncthreads();
        part[tid] += t;
        __syncthreads();
    }

    int run = part[tid] - sum;  // exclusive prefix at chunk start
    for (int i = beg; i < end; ++i) {
        row_ptr[i] = run;
        int d = deg[i];
        run += d;
        norm[i] = rsqrtf((float)max(d, 1));
    }
    if (tid == 0) row_ptr[n] = e_total;
}

// ---------------------------------------------------------------- bucket scatter
__global__ void bucket_kernel(const int* __restrict__ src, const int* __restrict__ dst,
                              const int* __restrict__ row_ptr, int* __restrict__ fill,
                              const float* __restrict__ norm,
                              int* __restrict__ src_sorted, float* __restrict__ w_sorted,
                              int e) {
    int i = blockIdx.x * blockDim.x + threadIdx.x;
    if (i < e) {
        int d = dst[i];
        int pos = row_ptr[d] + atomicAdd(&fill[d], 1);
        int s = src[i];
        src_sorted[pos] = s;
        w_sorted[pos]   = norm[s];   // pre-fold norm[src] into the edge weight
    }
}

// ---------------------------------------------------------------- propagation
// 1 wave (64 lanes) per node; lane = feature column. Each edge gather is a
// contiguous 256B row => fully coalesced. No atomics in the K-loop.
__global__ __launch_bounds__(256) void propagate_kernel(
        const float* __restrict__ h, const float* __restrict__ feat0,
        const int* __restrict__ row_ptr, const int* __restrict__ src_sorted,
        const float* __restrict__ w_sorted, const float* __restrict__ norm,
        float* __restrict__ h_out, int n) {
    const int node = blockIdx.x * (blockDim.x >> 6) + (threadIdx.x >> 6);
    if (node >= n) return;
    const int lane = threadIdx.x & 63;

    const int beg = row_ptr[node];
    const int end = row_ptr[node + 1];

    float acc = 0.0f;
    // 1-deep software pipeline: prefetch next edge's (src, w) while the
    // current edge's feature row is being gathered.
    int   s_next = 0;
    float w_next = 0.0f;
    if (beg < end) { s_next = src_sorted[beg]; w_next = w_sorted[beg]; }
    for (int e = beg; e < end; ) {
        int   s = s_next;
        float w = w_next;
        ++e;
        if (e < end) { s_next = src_sorted[e]; w_next = w_sorted[e]; }
        acc += h[s * D_FEAT + lane] * w;
    }

    const float nn  = norm[node];
    const int   idx = node * D_FEAT + lane;
    h_out[idx] = (1.0f - ALPHA) * nn * acc + ALPHA * feat0[idx];
}

// ---------------------------------------------------------------- launcher
static inline size_t align_up(size_t x, size_t a) { return (x + a - 1) & ~(a - 1); }

extern "C" void kernel_launch(void* const* d_in, const int* in_sizes, int n_in,
                              void* d_out, int out_size, void* d_ws, size_t ws_size,
                              hipStream_t stream) {
    const float* feat     = (const float*)d_in[0];
    const int*   edge_src = (const int*)d_in[1];
    const int*   edge_dst = (const int*)d_in[2];
    float*       out      = (float*)d_out;

    const int n = in_sizes[0] / D_FEAT;   // 100000
    const int e = in_sizes[1];            // 1000000

    // ---- workspace layout (all re-derived every call; ws is poisoned) ----
    char* ws = (char*)d_ws;
    int*   deg        = (int*)ws;          ws += align_up((size_t)n * 4, 256);
    int*   row_ptr    = (int*)ws;          ws += align_up((size_t)(n + 1) * 4, 256);
    float* norm       = (float*)ws;        ws += align_up((size_t)n * 4, 256);
    int*   fill       = (int*)ws;          ws += align_up((size_t)n * 4, 256);
    int*   src_sorted = (int*)ws;          ws += align_up((size_t)e * 4, 256);
    float* w_sorted   = (float*)ws;        ws += align_up((size_t)e * 4, 256);
    float* hA         = (float*)ws;        ws += align_up((size_t)n * D_FEAT * 4, 256);

    hipMemsetAsync(deg,  0, (size_t)n * 4, stream);
    hipMemsetAsync(fill, 0, (size_t)n * 4, stream);

    const int eb = 256, eg = (e + eb - 1) / eb;
    count_deg_kernel<<<eg, eb, 0, stream>>>(edge_dst, deg, e);
    scan_kernel<<<1, 1024, 0, stream>>>(deg, row_ptr, norm, n, e);
    bucket_kernel<<<eg, eb, 0, stream>>>(edge_src, edge_dst, row_ptr, fill, norm,
                                         src_sorted, w_sorted, e);

    // K iterations, ping-pong: odd iters -> hA, even iters -> d_out.
    // K=10 (even) => final result lands in d_out.
    const int waves_per_block = 4;                  // 256 threads
    const int pg = (n + waves_per_block - 1) / waves_per_block;
    const float* h_in = feat;
    for (int it = 1; it <= K_ITERS; ++it) {
        float* h_out = (it & 1) ? hA : out;
        propagate_kernel<<<pg, 256, 0, stream>>>(h_in, feat, row_ptr, src_sorted,
                                                 w_sorted, norm, h_out, n);
        h_in = h_out;
    }
}

// Round 3
// 689.652 us; speedup vs baseline: 1.7044x; 1.7044x over previous
//
#include <hip/hip_runtime.h>
#include <hip/hip_bf16.h>

// APPNP propagation on MI355X.
// R1: parallel hierarchical scan (was 230us single-block); propagate uses
// float4 x 16-lane quarter-waves => 4 edges in flight per node.
// R2: resubmit unchanged (R1 bench never ran: GPU acquisition timeout).

#define D_FEAT 64
#define K_ITERS 10
#define ALPHA 0.1f

#define SCAN_THREADS 4096   // 16 blocks x 256
#define SCAN_BLOCKS  16

// ---------------------------------------------------------------- degree count
__global__ void count_deg_kernel(const int* __restrict__ dst, int* __restrict__ deg, int e) {
    int i = blockIdx.x * blockDim.x + threadIdx.x;
    if (i < e) atomicAdd(&deg[dst[i]], 1);
}

// ------------------------------------------------------- scan stage 1: partials
__global__ void partial_sum_kernel(const int* __restrict__ deg, int* __restrict__ tsums, int n) {
    int t = blockIdx.x * blockDim.x + threadIdx.x;        // 0..4095
    int chunk = (n + SCAN_THREADS - 1) / SCAN_THREADS;
    int beg = t * chunk, end = min(beg + chunk, n);
    int s = 0;
    for (int i = beg; i < end; ++i) s += deg[i];
    tsums[t] = s;
}

// -------------------------------------------- scan stage 2: scan 4096 partials
__global__ void scan_partials_kernel(int* __restrict__ tsums) {
    __shared__ int part[1024];
    const int tid = threadIdx.x;
    int s0 = tsums[tid * 4 + 0], s1 = tsums[tid * 4 + 1];
    int s2 = tsums[tid * 4 + 2], s3 = tsums[tid * 4 + 3];
    int sum = s0 + s1 + s2 + s3;
    part[tid] = sum;
    __syncthreads();
    for (int off = 1; off < 1024; off <<= 1) {
        int t = (tid >= off) ? part[tid - off] : 0;
        __syncthreads();
        part[tid] += t;
        __syncthreads();
    }
    int ex = part[tid] - sum;   // exclusive prefix of this thread's group of 4
    tsums[tid * 4 + 0] = ex;
    tsums[tid * 4 + 1] = ex + s0;
    tsums[tid * 4 + 2] = ex + s0 + s1;
    tsums[tid * 4 + 3] = ex + s0 + s1 + s2;
}

// ------------------------------------------- scan stage 3: row_ptr + norm write
__global__ void write_rowptr_kernel(const int* __restrict__ deg, const int* __restrict__ tsums,
                                    int* __restrict__ row_ptr, float* __restrict__ norm,
                                    int n, int e_total) {
    int t = blockIdx.x * blockDim.x + threadIdx.x;
    int chunk = (n + SCAN_THREADS - 1) / SCAN_THREADS;
    int beg = t * chunk, end = min(beg + chunk, n);
    int run = tsums[t];
    for (int i = beg; i < end; ++i) {
        row_ptr[i] = run;
        int d = deg[i];
        run += d;
        norm[i] = rsqrtf((float)max(d, 1));
    }
    if (t == 0) row_ptr[n] = e_total;
}

// ---------------------------------------------------------------- bucket scatter
// (src, bitcast(norm[src])) packed into one int2 per edge.
__global__ void bucket_kernel(const int* __restrict__ src, const int* __restrict__ dst,
                              const int* __restrict__ row_ptr, int* __restrict__ fill,
                              const float* __restrict__ norm,
                              int2* __restrict__ edge_sw, int e) {
    int i = blockIdx.x * blockDim.x + threadIdx.x;
    if (i < e) {
        int d = dst[i];
        int pos = row_ptr[d] + atomicAdd(&fill[d], 1);
        int s = src[i];
        edge_sw[pos] = make_int2(s, __float_as_int(norm[s]));
    }
}

// ---------------------------------------------------------------- propagation
// 1 wave per node. 16 lanes cover the 64-float row as float4; the wave's 4
// quarter-waves gather 4 different edges concurrently (serial chain = deg/4).
// Cross-quarter reduce via shfl_xor(16), shfl_xor(32).
__global__ __launch_bounds__(256) void propagate_kernel(
        const float* __restrict__ h, const float* __restrict__ feat0,
        const int* __restrict__ row_ptr, const int2* __restrict__ edge_sw,
        const float* __restrict__ norm, float* __restrict__ h_out, int n) {
    const int node = blockIdx.x * 4 + (threadIdx.x >> 6);
    if (node >= n) return;
    const int lane = threadIdx.x & 63;
    const int q  = lane >> 4;    // quarter 0..3 -> which edge
    const int ql = lane & 15;    // feature group within row

    const int beg = row_ptr[node];
    const int end = row_ptr[node + 1];

    float4 acc = make_float4(0.f, 0.f, 0.f, 0.f);
    for (int e = beg + q; e < end; e += 4) {
        const int2  sw = edge_sw[e];
        const float w  = __int_as_float(sw.y);
        const float4 hv = *reinterpret_cast<const float4*>(&h[(size_t)sw.x * D_FEAT + ql * 4]);
        acc.x += hv.x * w;
        acc.y += hv.y * w;
        acc.z += hv.z * w;
        acc.w += hv.w * w;
    }

    // reduce the 4 quarter-wave partials (lanes l, l^16, l^32, l^48)
    acc.x += __shfl_xor(acc.x, 16); acc.y += __shfl_xor(acc.y, 16);
    acc.z += __shfl_xor(acc.z, 16); acc.w += __shfl_xor(acc.w, 16);
    acc.x += __shfl_xor(acc.x, 32); acc.y += __shfl_xor(acc.y, 32);
    acc.z += __shfl_xor(acc.z, 32); acc.w += __shfl_xor(acc.w, 32);

    if (q == 0) {
        const float nn  = norm[node];
        const int   idx = node * D_FEAT + ql * 4;
        const float4 f0 = *reinterpret_cast<const float4*>(&feat0[idx]);
        float4 o;
        o.x = (1.0f - ALPHA) * nn * acc.x + ALPHA * f0.x;
        o.y = (1.0f - ALPHA) * nn * acc.y + ALPHA * f0.y;
        o.z = (1.0f - ALPHA) * nn * acc.z + ALPHA * f0.z;
        o.w = (1.0f - ALPHA) * nn * acc.w + ALPHA * f0.w;
        *reinterpret_cast<float4*>(&h_out[idx]) = o;
    }
}

// ---------------------------------------------------------------- launcher
static inline size_t align_up(size_t x, size_t a) { return (x + a - 1) & ~(a - 1); }

extern "C" void kernel_launch(void* const* d_in, const int* in_sizes, int n_in,
                              void* d_out, int out_size, void* d_ws, size_t ws_size,
                              hipStream_t stream) {
    const float* feat     = (const float*)d_in[0];
    const int*   edge_src = (const int*)d_in[1];
    const int*   edge_dst = (const int*)d_in[2];
    float*       out      = (float*)d_out;

    const int n = in_sizes[0] / D_FEAT;   // 100000
    const int e = in_sizes[1];            // 1000000

    // ---- workspace layout (rebuilt every call; ws is poisoned) ----
    char* ws = (char*)d_ws;
    int*   deg     = (int*)ws;    ws += align_up((size_t)n * 4, 256);
    int*   row_ptr = (int*)ws;    ws += align_up((size_t)(n + 1) * 4, 256);
    float* norm    = (float*)ws;  ws += align_up((size_t)n * 4, 256);
    int*   fill    = (int*)ws;    ws += align_up((size_t)n * 4, 256);
    int*   tsums   = (int*)ws;    ws += align_up((size_t)SCAN_THREADS * 4, 256);
    int2*  edge_sw = (int2*)ws;   ws += align_up((size_t)e * 8, 256);
    float* hA      = (float*)ws;  ws += align_up((size_t)n * D_FEAT * 4, 256);

    hipMemsetAsync(deg,  0, (size_t)n * 4, stream);
    hipMemsetAsync(fill, 0, (size_t)n * 4, stream);

    const int eb = 256, eg = (e + eb - 1) / eb;
    count_deg_kernel<<<eg, eb, 0, stream>>>(edge_dst, deg, e);
    partial_sum_kernel<<<SCAN_BLOCKS, 256, 0, stream>>>(deg, tsums, n);
    scan_partials_kernel<<<1, 1024, 0, stream>>>(tsums);
    write_rowptr_kernel<<<SCAN_BLOCKS, 256, 0, stream>>>(deg, tsums, row_ptr, norm, n, e);
    bucket_kernel<<<eg, eb, 0, stream>>>(edge_src, edge_dst, row_ptr, fill, norm, edge_sw, e);

    // K iterations, ping-pong: odd iters -> hA, even iters -> d_out (K=10 even).
    const int pg = (n + 3) / 4;
    const float* h_in = feat;
    for (int it = 1; it <= K_ITERS; ++it) {
        float* h_out = (it & 1) ? hA : out;
        propagate_kernel<<<pg, 256, 0, stream>>>(h_in, feat, row_ptr, edge_sw, norm, h_out, n);
        h_in = h_out;
    }
}

// Round 13
// 585.678 us; speedup vs baseline: 2.0069x; 1.1775x over previous
//
#include <hip/hip_runtime.h>
#include <hip/hip_bf16.h>
#include <hip/hip_fp16.h>

// APPNP propagation on MI355X.
// R1: parallel hierarchical scan; float4 quarter-wave propagate.   690us
// R3: fp16 intermediate h (halves random-gather bytes = the measured
//     L2-miss-BW bottleneck) + 8-way edge parallelism per node wave.
// R5: bucket scatters 4B src only (was 8B int2; 66MB write-amp measured);
//     propagate reloads norm[s] from the L2-hot 400KB table.
// R6-R12: resubmit unchanged (never benched: GPU acquisition timeouts).

#define D_FEAT 64
#define K_ITERS 10
#define ALPHA 0.1f

#define SCAN_THREADS 4096   // 16 blocks x 256
#define SCAN_BLOCKS  16

// ---------------------------------------------------------------- degree count
__global__ void count_deg_kernel(const int* __restrict__ dst, int* __restrict__ deg, int e) {
    int i = blockIdx.x * blockDim.x + threadIdx.x;
    if (i < e) atomicAdd(&deg[dst[i]], 1);
}

// ------------------------------------------------------- scan stage 1: partials
__global__ void partial_sum_kernel(const int* __restrict__ deg, int* __restrict__ tsums, int n) {
    int t = blockIdx.x * blockDim.x + threadIdx.x;        // 0..4095
    int chunk = (n + SCAN_THREADS - 1) / SCAN_THREADS;
    int beg = t * chunk, end = min(beg + chunk, n);
    int s = 0;
    for (int i = beg; i < end; ++i) s += deg[i];
    tsums[t] = s;
}

// -------------------------------------------- scan stage 2: scan 4096 partials
__global__ void scan_partials_kernel(int* __restrict__ tsums) {
    __shared__ int part[1024];
    const int tid = threadIdx.x;
    int s0 = tsums[tid * 4 + 0], s1 = tsums[tid * 4 + 1];
    int s2 = tsums[tid * 4 + 2], s3 = tsums[tid * 4 + 3];
    int sum = s0 + s1 + s2 + s3;
    part[tid] = sum;
    __syncthreads();
    for (int off = 1; off < 1024; off <<= 1) {
        int t = (tid >= off) ? part[tid - off] : 0;
        __syncthreads();
        part[tid] += t;
        __syncthreads();
    }
    int ex = part[tid] - sum;
    tsums[tid * 4 + 0] = ex;
    tsums[tid * 4 + 1] = ex + s0;
    tsums[tid * 4 + 2] = ex + s0 + s1;
    tsums[tid * 4 + 3] = ex + s0 + s1 + s2;
}

// ------------------------------------------- scan stage 3: row_ptr + norm write
__global__ void write_rowptr_kernel(const int* __restrict__ deg, const int* __restrict__ tsums,
                                    int* __restrict__ row_ptr, float* __restrict__ norm,
                                    int n, int e_total) {
    int t = blockIdx.x * blockDim.x + threadIdx.x;
    int chunk = (n + SCAN_THREADS - 1) / SCAN_THREADS;
    int beg = t * chunk, end = min(beg + chunk, n);
    int run = tsums[t];
    for (int i = beg; i < end; ++i) {
        row_ptr[i] = run;
        int d = deg[i];
        run += d;
        norm[i] = rsqrtf((float)max(d, 1));
    }
    if (t == 0) row_ptr[n] = e_total;
}

// ---------------------------------------------------------------- bucket scatter
// 4B per edge: src index only (weight re-derived in propagate from norm table).
__global__ void bucket_kernel(const int* __restrict__ src, const int* __restrict__ dst,
                              const int* __restrict__ row_ptr, int* __restrict__ fill,
                              int* __restrict__ src_sorted, int e) {
    int i = blockIdx.x * blockDim.x + threadIdx.x;
    if (i < e) {
        int d = dst[i];
        int pos = row_ptr[d] + atomicAdd(&fill[d], 1);
        src_sorted[pos] = src[i];
    }
}

// -------------------------------------------------------------- fp32 -> fp16
__global__ void f32_to_f16_kernel(const float* __restrict__ in, __half* __restrict__ out,
                                  int n4 /* count of float4 groups */) {
    int i = blockIdx.x * blockDim.x + threadIdx.x;
    if (i < n4) {
        float4 v = reinterpret_cast<const float4*>(in)[i];
        __half2 a = __floats2half2_rn(v.x, v.y);
        __half2 b = __floats2half2_rn(v.z, v.w);
        uint2 o;
        o.x = *reinterpret_cast<unsigned int*>(&a);
        o.y = *reinterpret_cast<unsigned int*>(&b);
        reinterpret_cast<uint2*>(out)[i] = o;
    }
}

// ---------------------------------------------------------------- propagation
// 1 wave per node. Row is fp16 (128B): 8 lanes x 16B cover one row, so the
// wave's 8 groups gather 8 edges concurrently (serial chain = ceil(deg/8)).
// fp32 accumulate; reduce across groups via shfl_xor(8,16,32).
template<bool FINAL>
__global__ __launch_bounds__(256) void propagate_kernel(
        const __half* __restrict__ h, const float* __restrict__ feat0,
        const int* __restrict__ row_ptr, const int* __restrict__ src_sorted,
        const float* __restrict__ norm,
        __half* __restrict__ out_h, float* __restrict__ out_f, int n) {
    const int node = blockIdx.x * 4 + (threadIdx.x >> 6);
    if (node >= n) return;
    const int lane = threadIdx.x & 63;
    const int g   = lane >> 3;   // edge group 0..7
    const int sub = lane & 7;    // 16B chunk within the 128B row

    const int beg = row_ptr[node];
    const int end = row_ptr[node + 1];

    float acc[8] = {0.f, 0.f, 0.f, 0.f, 0.f, 0.f, 0.f, 0.f};
    for (int e = beg + g; e < end; e += 8) {
        const int   s = src_sorted[e];
        const float w = norm[s];           // 400KB table, L2/L3-hot
        uint4 raw = *reinterpret_cast<const uint4*>(h + (size_t)s * D_FEAT + sub * 8);
        __half2 p0 = *reinterpret_cast<__half2*>(&raw.x);
        __half2 p1 = *reinterpret_cast<__half2*>(&raw.y);
        __half2 p2 = *reinterpret_cast<__half2*>(&raw.z);
        __half2 p3 = *reinterpret_cast<__half2*>(&raw.w);
        float2 f0 = __half22float2(p0), f1 = __half22float2(p1);
        float2 f2 = __half22float2(p2), f3 = __half22float2(p3);
        acc[0] += f0.x * w; acc[1] += f0.y * w;
        acc[2] += f1.x * w; acc[3] += f1.y * w;
        acc[4] += f2.x * w; acc[5] += f2.y * w;
        acc[6] += f3.x * w; acc[7] += f3.y * w;
    }

    // reduce the 8 per-group partials (lanes differing in bits 3..5)
    #pragma unroll
    for (int off = 8; off <= 32; off <<= 1) {
        #pragma unroll
        for (int i = 0; i < 8; ++i) acc[i] += __shfl_xor(acc[i], off);
    }

    if (g == 0) {
        const float s = (1.0f - ALPHA) * norm[node];
        const size_t base = (size_t)node * D_FEAT + sub * 8;
        const float4 fa = *reinterpret_cast<const float4*>(feat0 + base);
        const float4 fb = *reinterpret_cast<const float4*>(feat0 + base + 4);
        float o[8];
        o[0] = s * acc[0] + ALPHA * fa.x;  o[1] = s * acc[1] + ALPHA * fa.y;
        o[2] = s * acc[2] + ALPHA * fa.z;  o[3] = s * acc[3] + ALPHA * fa.w;
        o[4] = s * acc[4] + ALPHA * fb.x;  o[5] = s * acc[5] + ALPHA * fb.y;
        o[6] = s * acc[6] + ALPHA * fb.z;  o[7] = s * acc[7] + ALPHA * fb.w;
        if (FINAL) {
            float4 w0 = make_float4(o[0], o[1], o[2], o[3]);
            float4 w1 = make_float4(o[4], o[5], o[6], o[7]);
            *reinterpret_cast<float4*>(out_f + base)     = w0;
            *reinterpret_cast<float4*>(out_f + base + 4) = w1;
        } else {
            __half2 h0 = __floats2half2_rn(o[0], o[1]);
            __half2 h1 = __floats2half2_rn(o[2], o[3]);
            __half2 h2 = __floats2half2_rn(o[4], o[5]);
            __half2 h3 = __floats2half2_rn(o[6], o[7]);
            uint4 w;
            w.x = *reinterpret_cast<unsigned int*>(&h0);
            w.y = *reinterpret_cast<unsigned int*>(&h1);
            w.z = *reinterpret_cast<unsigned int*>(&h2);
            w.w = *reinterpret_cast<unsigned int*>(&h3);
            *reinterpret_cast<uint4*>(out_h + base) = w;
        }
    }
}

// ---------------------------------------------------------------- launcher
static inline size_t align_up(size_t x, size_t a) { return (x + a - 1) & ~(a - 1); }

extern "C" void kernel_launch(void* const* d_in, const int* in_sizes, int n_in,
                              void* d_out, int out_size, void* d_ws, size_t ws_size,
                              hipStream_t stream) {
    const float* feat     = (const float*)d_in[0];
    const int*   edge_src = (const int*)d_in[1];
    const int*   edge_dst = (const int*)d_in[2];
    float*       out      = (float*)d_out;

    const int n = in_sizes[0] / D_FEAT;   // 100000
    const int e = in_sizes[1];            // 1000000

    // ---- workspace layout (rebuilt every call; ws is poisoned) ----
    char* ws = (char*)d_ws;
    int*    deg        = (int*)ws;    ws += align_up((size_t)n * 4, 256);
    int*    row_ptr    = (int*)ws;    ws += align_up((size_t)(n + 1) * 4, 256);
    float*  norm       = (float*)ws;  ws += align_up((size_t)n * 4, 256);
    int*    fill       = (int*)ws;    ws += align_up((size_t)n * 4, 256);
    int*    tsums      = (int*)ws;    ws += align_up((size_t)SCAN_THREADS * 4, 256);
    int*    src_sorted = (int*)ws;    ws += align_up((size_t)e * 4, 256);
    __half* hA         = (__half*)ws; ws += align_up((size_t)n * D_FEAT * 2, 256);
    __half* hB         = (__half*)ws; ws += align_up((size_t)n * D_FEAT * 2, 256);

    hipMemsetAsync(deg,  0, (size_t)n * 4, stream);
    hipMemsetAsync(fill, 0, (size_t)n * 4, stream);

    const int eb = 256, eg = (e + eb - 1) / eb;
    count_deg_kernel<<<eg, eb, 0, stream>>>(edge_dst, deg, e);
    partial_sum_kernel<<<SCAN_BLOCKS, 256, 0, stream>>>(deg, tsums, n);
    scan_partials_kernel<<<1, 1024, 0, stream>>>(tsums);
    write_rowptr_kernel<<<SCAN_BLOCKS, 256, 0, stream>>>(deg, tsums, row_ptr, norm, n, e);
    bucket_kernel<<<eg, eb, 0, stream>>>(edge_src, edge_dst, row_ptr, fill, src_sorted, e);

    // feat -> fp16 seed buffer hB
    const int n4 = n * D_FEAT / 4;
    f32_to_f16_kernel<<<(n4 + 255) / 256, 256, 0, stream>>>(feat, hB, n4);

    // K iterations: 1..K-1 ping-pong fp16 (hB -> hA -> hB -> ...), K -> fp32 out.
    const int pg = (n + 3) / 4;
    const __half* h_in = hB;
    for (int it = 1; it < K_ITERS; ++it) {
        __half* h_out = (it & 1) ? hA : hB;
        propagate_kernel<false><<<pg, 256, 0, stream>>>(h_in, feat, row_ptr, src_sorted,
                                                        norm, h_out, nullptr, n);
        h_in = h_out;
    }
    propagate_kernel<true><<<pg, 256, 0, stream>>>(h_in, feat, row_ptr, src_sorted,
                                                   norm, nullptr, out, n);
}

// Round 14
// 582.423 us; speedup vs baseline: 2.0182x; 1.0056x over previous
//
#include <hip/hip_runtime.h>
#include <hip/hip_bf16.h>
#include <hip/hip_fp16.h>

// APPNP propagation on MI355X.
// R1:  parallel scan; float4 quarter-wave propagate.                690us
// R3:  fp16 intermediate h + 8-way edge parallelism.
// R5:  4B bucket scatter + norm[s] reload.                          586us
// R14: REVERT R5's bucket (measured 54->70us regression; 4B scatter has the
//      same dirty-line write-amp as 8B and adds a dependent norm gather to
//      propagate). Back to int2 (src, w) scatter. Plus: fp16 feat0 copy for
//      the alpha term (saves 12.8MB/iter fp32 streaming).

#define D_FEAT 64
#define K_ITERS 10
#define ALPHA 0.1f

#define SCAN_THREADS 4096   // 16 blocks x 256
#define SCAN_BLOCKS  16

// ---------------------------------------------------------------- degree count
__global__ void count_deg_kernel(const int* __restrict__ dst, int* __restrict__ deg, int e) {
    int i = blockIdx.x * blockDim.x + threadIdx.x;
    if (i < e) atomicAdd(&deg[dst[i]], 1);
}

// ------------------------------------------------------- scan stage 1: partials
__global__ void partial_sum_kernel(const int* __restrict__ deg, int* __restrict__ tsums, int n) {
    int t = blockIdx.x * blockDim.x + threadIdx.x;        // 0..4095
    int chunk = (n + SCAN_THREADS - 1) / SCAN_THREADS;
    int beg = t * chunk, end = min(beg + chunk, n);
    int s = 0;
    for (int i = beg; i < end; ++i) s += deg[i];
    tsums[t] = s;
}

// -------------------------------------------- scan stage 2: scan 4096 partials
__global__ void scan_partials_kernel(int* __restrict__ tsums) {
    __shared__ int part[1024];
    const int tid = threadIdx.x;
    int s0 = tsums[tid * 4 + 0], s1 = tsums[tid * 4 + 1];
    int s2 = tsums[tid * 4 + 2], s3 = tsums[tid * 4 + 3];
    int sum = s0 + s1 + s2 + s3;
    part[tid] = sum;
    __syncthreads();
    for (int off = 1; off < 1024; off <<= 1) {
        int t = (tid >= off) ? part[tid - off] : 0;
        __syncthreads();
        part[tid] += t;
        __syncthreads();
    }
    int ex = part[tid] - sum;
    tsums[tid * 4 + 0] = ex;
    tsums[tid * 4 + 1] = ex + s0;
    tsums[tid * 4 + 2] = ex + s0 + s1;
    tsums[tid * 4 + 3] = ex + s0 + s1 + s2;
}

// ------------------------------------------- scan stage 3: row_ptr + norm write
__global__ void write_rowptr_kernel(const int* __restrict__ deg, const int* __restrict__ tsums,
                                    int* __restrict__ row_ptr, float* __restrict__ norm,
                                    int n, int e_total) {
    int t = blockIdx.x * blockDim.x + threadIdx.x;
    int chunk = (n + SCAN_THREADS - 1) / SCAN_THREADS;
    int beg = t * chunk, end = min(beg + chunk, n);
    int run = tsums[t];
    for (int i = beg; i < end; ++i) {
        row_ptr[i] = run;
        int d = deg[i];
        run += d;
        norm[i] = rsqrtf((float)max(d, 1));
    }
    if (t == 0) row_ptr[n] = e_total;
}

// ---------------------------------------------------------------- bucket scatter
// int2 (src, bitcast(norm[src])) per edge — measured faster than 4B-only (R13).
__global__ void bucket_kernel(const int* __restrict__ src, const int* __restrict__ dst,
                              const int* __restrict__ row_ptr, int* __restrict__ fill,
                              const float* __restrict__ norm,
                              int2* __restrict__ edge_sw, int e) {
    int i = blockIdx.x * blockDim.x + threadIdx.x;
    if (i < e) {
        int d = dst[i];
        int pos = row_ptr[d] + atomicAdd(&fill[d], 1);
        int s = src[i];
        edge_sw[pos] = make_int2(s, __float_as_int(norm[s]));
    }
}

// -------------------------------------------------------------- fp32 -> fp16
__global__ void f32_to_f16_kernel(const float* __restrict__ in, __half* __restrict__ out,
                                  int n4 /* count of float4 groups */) {
    int i = blockIdx.x * blockDim.x + threadIdx.x;
    if (i < n4) {
        float4 v = reinterpret_cast<const float4*>(in)[i];
        __half2 a = __floats2half2_rn(v.x, v.y);
        __half2 b = __floats2half2_rn(v.z, v.w);
        uint2 o;
        o.x = *reinterpret_cast<unsigned int*>(&a);
        o.y = *reinterpret_cast<unsigned int*>(&b);
        reinterpret_cast<uint2*>(out)[i] = o;
    }
}

// ---------------------------------------------------------------- propagation
// 1 wave per node. fp16 rows (128B): 8 lanes x 16B per row; the wave's 8
// groups gather 8 edges concurrently. fp32 accumulate; shfl_xor reduce.
// feat0 alpha-term read from the fp16 read-only copy (halves that stream).
template<bool FINAL>
__global__ __launch_bounds__(256) void propagate_kernel(
        const __half* __restrict__ h, const __half* __restrict__ feat0h,
        const int* __restrict__ row_ptr, const int2* __restrict__ edge_sw,
        const float* __restrict__ norm,
        __half* __restrict__ out_h, float* __restrict__ out_f, int n) {
    const int node = blockIdx.x * 4 + (threadIdx.x >> 6);
    if (node >= n) return;
    const int lane = threadIdx.x & 63;
    const int g   = lane >> 3;   // edge group 0..7
    const int sub = lane & 7;    // 16B chunk within the 128B row

    const int beg = row_ptr[node];
    const int end = row_ptr[node + 1];

    float acc[8] = {0.f, 0.f, 0.f, 0.f, 0.f, 0.f, 0.f, 0.f};
    for (int e = beg + g; e < end; e += 8) {
        const int2  sw = edge_sw[e];
        const float w  = __int_as_float(sw.y);
        uint4 raw = *reinterpret_cast<const uint4*>(h + (size_t)sw.x * D_FEAT + sub * 8);
        __half2 p0 = *reinterpret_cast<__half2*>(&raw.x);
        __half2 p1 = *reinterpret_cast<__half2*>(&raw.y);
        __half2 p2 = *reinterpret_cast<__half2*>(&raw.z);
        __half2 p3 = *reinterpret_cast<__half2*>(&raw.w);
        float2 f0 = __half22float2(p0), f1 = __half22float2(p1);
        float2 f2 = __half22float2(p2), f3 = __half22float2(p3);
        acc[0] += f0.x * w; acc[1] += f0.y * w;
        acc[2] += f1.x * w; acc[3] += f1.y * w;
        acc[4] += f2.x * w; acc[5] += f2.y * w;
        acc[6] += f3.x * w; acc[7] += f3.y * w;
    }

    // reduce the 8 per-group partials (lanes differing in bits 3..5)
    #pragma unroll
    for (int off = 8; off <= 32; off <<= 1) {
        #pragma unroll
        for (int i = 0; i < 8; ++i) acc[i] += __shfl_xor(acc[i], off);
    }

    if (g == 0) {
        const float s = (1.0f - ALPHA) * norm[node];
        const size_t base = (size_t)node * D_FEAT + sub * 8;
        // alpha-term from the fp16 read-only feat0 copy
        uint4 raw = *reinterpret_cast<const uint4*>(feat0h + base);
        __half2 q0 = *reinterpret_cast<__half2*>(&raw.x);
        __half2 q1 = *reinterpret_cast<__half2*>(&raw.y);
        __half2 q2 = *reinterpret_cast<__half2*>(&raw.z);
        __half2 q3 = *reinterpret_cast<__half2*>(&raw.w);
        float2 f0 = __half22float2(q0), f1 = __half22float2(q1);
        float2 f2 = __half22float2(q2), f3 = __half22float2(q3);
        float o[8];
        o[0] = s * acc[0] + ALPHA * f0.x;  o[1] = s * acc[1] + ALPHA * f0.y;
        o[2] = s * acc[2] + ALPHA * f1.x;  o[3] = s * acc[3] + ALPHA * f1.y;
        o[4] = s * acc[4] + ALPHA * f2.x;  o[5] = s * acc[5] + ALPHA * f2.y;
        o[6] = s * acc[6] + ALPHA * f3.x;  o[7] = s * acc[7] + ALPHA * f3.y;
        if (FINAL) {
            float4 w0 = make_float4(o[0], o[1], o[2], o[3]);
            float4 w1 = make_float4(o[4], o[5], o[6], o[7]);
            *reinterpret_cast<float4*>(out_f + base)     = w0;
            *reinterpret_cast<float4*>(out_f + base + 4) = w1;
        } else {
            __half2 h0 = __floats2half2_rn(o[0], o[1]);
            __half2 h1 = __floats2half2_rn(o[2], o[3]);
            __half2 h2 = __floats2half2_rn(o[4], o[5]);
            __half2 h3 = __floats2half2_rn(o[6], o[7]);
            uint4 w;
            w.x = *reinterpret_cast<unsigned int*>(&h0);
            w.y = *reinterpret_cast<unsigned int*>(&h1);
            w.z = *reinterpret_cast<unsigned int*>(&h2);
            w.w = *reinterpret_cast<unsigned int*>(&h3);
            *reinterpret_cast<uint4*>(out_h + base) = w;
        }
    }
}

// ---------------------------------------------------------------- launcher
static inline size_t align_up(size_t x, size_t a) { return (x + a - 1) & ~(a - 1); }

extern "C" void kernel_launch(void* const* d_in, const int* in_sizes, int n_in,
                              void* d_out, int out_size, void* d_ws, size_t ws_size,
                              hipStream_t stream) {
    const float* feat     = (const float*)d_in[0];
    const int*   edge_src = (const int*)d_in[1];
    const int*   edge_dst = (const int*)d_in[2];
    float*       out      = (float*)d_out;

    const int n = in_sizes[0] / D_FEAT;   // 100000
    const int e = in_sizes[1];            // 1000000

    // ---- workspace layout (rebuilt every call; ws is poisoned) ----
    char* ws = (char*)d_ws;
    int*    deg     = (int*)ws;    ws += align_up((size_t)n * 4, 256);
    int*    row_ptr = (int*)ws;    ws += align_up((size_t)(n + 1) * 4, 256);
    float*  norm    = (float*)ws;  ws += align_up((size_t)n * 4, 256);
    int*    fill    = (int*)ws;    ws += align_up((size_t)n * 4, 256);
    int*    tsums   = (int*)ws;    ws += align_up((size_t)SCAN_THREADS * 4, 256);
    int2*   edge_sw = (int2*)ws;   ws += align_up((size_t)e * 8, 256);
    __half* hF      = (__half*)ws; ws += align_up((size_t)n * D_FEAT * 2, 256); // feat0 fp16, read-only
    __half* hA      = (__half*)ws; ws += align_up((size_t)n * D_FEAT * 2, 256);
    __half* hB      = (__half*)ws; ws += align_up((size_t)n * D_FEAT * 2, 256);

    hipMemsetAsync(deg,  0, (size_t)n * 4, stream);
    hipMemsetAsync(fill, 0, (size_t)n * 4, stream);

    const int eb = 256, eg = (e + eb - 1) / eb;
    count_deg_kernel<<<eg, eb, 0, stream>>>(edge_dst, deg, e);
    partial_sum_kernel<<<SCAN_BLOCKS, 256, 0, stream>>>(deg, tsums, n);
    scan_partials_kernel<<<1, 1024, 0, stream>>>(tsums);
    write_rowptr_kernel<<<SCAN_BLOCKS, 256, 0, stream>>>(deg, tsums, row_ptr, norm, n, e);
    bucket_kernel<<<eg, eb, 0, stream>>>(edge_src, edge_dst, row_ptr, fill, norm, edge_sw, e);

    // feat -> fp16 read-only copy hF (seed + alpha term)
    const int n4 = n * D_FEAT / 4;
    f32_to_f16_kernel<<<(n4 + 255) / 256, 256, 0, stream>>>(feat, hF, n4);

    // K iterations: it=1 reads hF; 2..9 ping-pong hA/hB; it=10 -> fp32 out.
    const int pg = (n + 3) / 4;
    const __half* h_in = hF;
    for (int it = 1; it < K_ITERS; ++it) {
        __half* h_out = (it & 1) ? hA : hB;
        propagate_kernel<false><<<pg, 256, 0, stream>>>(h_in, hF, row_ptr, edge_sw,
                                                        norm, h_out, nullptr, n);
        h_in = h_out;
    }
    propagate_kernel<true><<<pg, 256, 0, stream>>>(h_in, hF, row_ptr, edge_sw,
                                                   norm, nullptr, out, n);
}